// Round 11
// baseline (1974.197 us; speedup 1.0000x reference)
//
#include <hip/hip_runtime.h>
#include <hip/hip_bf16.h>
#include <math.h>

// Problem constants
#define BB 32
#define TT 12
#define NN 512
#define HH 64
#define DIN 65
#define MSUB 96        // ROWS/16 (ROWS = 3*512)
#define RTOT 16384     // BB*NN dense rows
#define PSUB 5         // 80 padded cols per batch
#define STGBUF 17408   // f16 per staging buffer (34 subtiles x 512)
#define NBLK 256u

typedef _Float16 f16;
typedef f16 f16x8 __attribute__((ext_vector_type(8)));
typedef float f32x4 __attribute__((ext_vector_type(4)));

#define GLD_LDS16(g, l) \
    __builtin_amdgcn_global_load_lds((const __attribute__((address_space(1))) void*)(g), \
                                     (__attribute__((address_space(3))) void*)(l), 16, 0, 0)

// Bf element address: node j (K-dim), batch b, local col p in [0,80)
__device__ __forceinline__ size_t bf_addr(int j, int b, int p) {
    return ((size_t)(((j >> 5) * 32 + b) * PSUB + (p >> 4)) * 64 + ((j >> 3) & 3) * 16 + (p & 15)) * 8 + (j & 7);
}

// ---------------- device-scope grid barrier (sense-reversing, bar[0]=count bar[1]=gen) --------
__device__ __forceinline__ void gbar(unsigned* bar, int tid) {
    __syncthreads();
    if (tid == 0) {
        __threadfence();  // release this block's prior global writes
        unsigned my = __hip_atomic_load(&bar[1], __ATOMIC_RELAXED, __HIP_MEMORY_SCOPE_AGENT);
        unsigned a = __hip_atomic_fetch_add(&bar[0], 1u, __ATOMIC_ACQ_REL, __HIP_MEMORY_SCOPE_AGENT);
        if (a + 1u == NBLK) {
            __hip_atomic_store(&bar[0], 0u, __ATOMIC_RELAXED, __HIP_MEMORY_SCOPE_AGENT);
            __hip_atomic_fetch_add(&bar[1], 1u, __ATOMIC_RELEASE, __HIP_MEMORY_SCOPE_AGENT);
        } else {
            while (__hip_atomic_load(&bar[1], __ATOMIC_ACQUIRE, __HIP_MEMORY_SCOPE_AGENT) == my)
                __builtin_amdgcn_s_sleep(4);
        }
        __threadfence();
    }
    __syncthreads();
}

// ---------------- convert P (f32, 1536x512 row-major) -> fragment-major f16 A ----------------
__global__ __launch_bounds__(256) void conv_a(const float* __restrict__ P, f16* __restrict__ Af) {
    int u = blockIdx.x * 256 + threadIdx.x;  // 1536*512/8 slots
    int lane = u & 63;
    int su = u >> 6;
    int ks = su / MSUB, ms = su - ks * MSUB;
    int m = ms * 16 + (lane & 15);
    int k = ks * 32 + (lane >> 4) * 8;
    const float* src = &P[(size_t)m * 512 + k];
    f16x8 v;
#pragma unroll
    for (int i = 0; i < 8; ++i) v[i] = (f16)src[i];
    *(f16x8*)&Af[(size_t)u * 8] = v;
}

// -------- convert dense weight (195 x O f32) -> K-permuted fragment pack matching in-reg S^T --
__global__ __launch_bounds__(256) void conv_w(const float* __restrict__ W, int O, int OS,
                                              f16* __restrict__ Wf) {
    int u = blockIdx.x * 256 + threadIdx.x;
    if (u >= 8 * OS * 64) return;
    int lane = u & 63, slot = u >> 6;
    int s = slot / OS, os = slot - s * OS;
    int o = os * 16 + (lane & 15);
    int g = lane >> 4;
    f16x8 v;
#pragma unroll
    for (int i = 0; i < 8; ++i) {
        int f = 2 * s + (i >= 4 ? 1 : 0);
        int kl = f / 5, ps = f - kl * 5;
        int p = ps * 16 + 4 * g + (i & 3);
        v[i] = (f < 15 && p < 65) ? (f16)W[(size_t)(kl * 65 + p) * O + o] : (f16)0.f;
    }
    *(f16x8*)&Wf[(size_t)u * 8] = v;
}

// ---------------- write x[b,0,:,0] into Bf p=0 col (prologue) ----------------
__global__ __launch_bounds__(256) void upd_x(const float* __restrict__ x, int t,
                                             f16* __restrict__ Bf) {
    int idx = blockIdx.x * 256 + threadIdx.x;
    if (idx >= RTOT) return;
    int b = idx >> 9, n = idx & 511;
    Bf[bf_addr(n, b, 0)] = (f16)x[((size_t)b * TT + t) * NN + n];
}

// ---------------- staging: 34 slots (24 A, 10 B), waves take 9/9/8/8 ----------------
__device__ __forceinline__ void stage_tile(const f16* __restrict__ Af,
                                           const f16* __restrict__ BfIn,
                                           f16* __restrict__ lds,
                                           int b, int mb, int wave, int lane, int d, int it) {
#pragma unroll
    for (int qi = 0; qi < 9; ++qi) {
        int q = qi * 4 + wave;
        if (q < 34) {
            const f16* src;
            if (q < 24) {
                int ksl = q / 12, aid = q % 12;
                int msub = (aid >> 2) * 32 + mb * 4 + (aid & 3);
                src = &Af[((size_t)((it * 2 + ksl) * MSUB + msub) * 64 + lane) * 8];
            } else {
                int qb = q - 24;
                int ksl = qb / 5, ps = qb - ksl * 5;
                src = &BfIn[((size_t)(((it * 2 + ksl) * 32 + b) * PSUB + ps) * 64 + lane) * 8];
            }
            GLD_LDS16(src, &lds[d * STGBUF + q * 512 + lane * 8]);
        }
    }
}

// ---------------- mm: S^T chunk for (batch b, node-band mb) into acc[15] ----------------
__device__ __forceinline__ void gcn_mm(const f16* __restrict__ Af,
                                       const f16* __restrict__ BfIn,
                                       f16* __restrict__ lds,
                                       int b, int mb, int wave, int lane,
                                       f32x4 (&acc)[15]) {
    stage_tile(Af, BfIn, lds, b, mb, wave, lane, 0, 0);
#pragma unroll 1
    for (int it = 0; it < 8; ++it) {
        int d = it & 1;
        __syncthreads();
        if (it < 7) stage_tile(Af, BfIn, lds, b, mb, wave, lane, d ^ 1, it + 1);
#pragma unroll
        for (int s = 0; s < 2; ++s) {
            f16x8 bfr[5], afr[3];
#pragma unroll
            for (int ps = 0; ps < PSUB; ++ps)
                bfr[ps] = *(const f16x8*)&lds[d * STGBUF + (24 + s * 5 + ps) * 512 + lane * 8];
#pragma unroll
            for (int k = 0; k < 3; ++k)
                afr[k] = *(const f16x8*)&lds[d * STGBUF + (s * 12 + k * 4 + wave) * 512 + lane * 8];
#pragma unroll
            for (int k = 0; k < 3; ++k)
#pragma unroll
                for (int ps = 0; ps < PSUB; ++ps)
                    acc[k * 5 + ps] = __builtin_amdgcn_mfma_f32_16x16x32_f16(bfr[ps], afr[k], acc[k * 5 + ps], 0, 0, 0);
        }
    }
}

// build dense A-operand fragments from acc (K-permuted to match conv_w)
__device__ __forceinline__ void build_ad(const f32x4 (&acc)[15], f16x8 (&ad)[8]) {
#pragma unroll
    for (int s = 0; s < 8; ++s)
#pragma unroll
        for (int i = 0; i < 4; ++i) {
            ad[s][i] = (f16)acc[2 * s][i];
            ad[s][4 + i] = (s < 7) ? (f16)acc[2 * s + 1][i] : (f16)0.f;
        }
}

// ---------------- persistent kernel: whole encoder+decoder, h/z in registers ----------------
__global__ __launch_bounds__(256, 1) void persist(const f16* __restrict__ Af,
                                                  f16* __restrict__ BfA,
                                                  f16* __restrict__ BfB,
                                                  const f16* __restrict__ WfGe,
                                                  const f16* __restrict__ WfCe,
                                                  const f16* __restrict__ WfGd,
                                                  const f16* __restrict__ WfCd,
                                                  const float* __restrict__ beg,
                                                  const float* __restrict__ beu,
                                                  const float* __restrict__ bdg,
                                                  const float* __restrict__ bdu,
                                                  const float* __restrict__ x,
                                                  const float* __restrict__ Wp,
                                                  const float* __restrict__ bp,
                                                  float* __restrict__ outp,
                                                  int hor,
                                                  unsigned* __restrict__ bar) {
    __shared__ f16 lds[2 * STGBUF];
    int tid = threadIdx.x, wave = tid >> 6, lane = tid & 63;
    int b = blockIdx.x >> 3, mb = blockIdx.x & 7;
    int o_l = lane & 15, g = lane >> 4;
    int node0 = mb * 64 + wave * 16;

    f32x4 hreg[4] = {};  // h[n=node0+4g+rI][o=os*16+o_l], persistent across cells
    f32x4 zreg[4];       // z, gates -> cand within a cell

    int ncell = TT + hor;
    for (int cell = 0; cell < ncell; ++cell) {
        bool enc = cell < TT;
        const f16* Wg = enc ? WfGe : WfGd;
        const float* bg = enc ? beg : bdg;
        const f16* Wc = enc ? WfCe : WfCd;
        const float* bc = enc ? beu : bdu;

        // ======== gates phase: mm(BfA) + zr-dense; z->zreg, r*h->BfB; p0 copy ========
        {
            f32x4 acc[15] = {};
            gcn_mm(Af, BfA, lds, b, mb, wave, lane, acc);
            f16x8 ad[8];
            build_ad(acc, ad);

            __syncthreads();  // staging reads done; reuse lds for W
#pragma unroll
            for (int qi = 0; qi < 16; ++qi) {
                int q = qi * 4 + wave;  // 64 W subtiles
                GLD_LDS16(&Wg[((size_t)q * 64 + lane) * 8], &lds[q * 512 + lane * 8]);
            }
            __syncthreads();

            f32x4 acc2[8] = {};
#pragma unroll
            for (int s = 0; s < 8; ++s)
#pragma unroll
                for (int os = 0; os < 8; ++os) {
                    f16x8 w = *(const f16x8*)&lds[(s * 8 + os) * 512 + lane * 8];
                    acc2[os] = __builtin_amdgcn_mfma_f32_16x16x32_f16(ad[s], w, acc2[os], 0, 0, 0);
                }

#pragma unroll
            for (int os = 0; os < 4; ++os)  // z -> regs
#pragma unroll
                for (int rI = 0; rI < 4; ++rI)
                    zreg[os][rI] = 1.f / (1.f + expf(-(acc2[os][rI] + bg[os * 16 + o_l])));
#pragma unroll
            for (int os = 4; os < 8; ++os) {  // r -> r*h into BfB
                int osh = os - 4;
#pragma unroll
                for (int rI = 0; rI < 4; ++rI) {
                    float rr = 1.f / (1.f + expf(-(acc2[os][rI] + bg[64 + osh * 16 + o_l])));
                    int n = node0 + 4 * g + rI;
                    BfB[bf_addr(n, b, 1 + osh * 16 + o_l)] = (f16)(rr * hreg[osh][rI]);
                }
            }
            if (tid < 64) {  // p0 col copy (x or go)
                int n = mb * 64 + tid;
                BfB[bf_addr(n, b, 0)] = BfA[bf_addr(n, b, 0)];
            }
        }
        gbar(bar, tid);

        // ======== cand phase: mm(BfB) + cand-dense + GRU update; h->regs+BfA; tail ========
        {
            f32x4 acc[15] = {};
            gcn_mm(Af, BfB, lds, b, mb, wave, lane, acc);
            f16x8 ad[8];
            build_ad(acc, ad);

            __syncthreads();
#pragma unroll
            for (int qi = 0; qi < 8; ++qi) {
                int q = qi * 4 + wave;  // 32 W subtiles
                GLD_LDS16(&Wc[((size_t)q * 64 + lane) * 8], &lds[q * 512 + lane * 8]);
            }
            __syncthreads();

            f32x4 acc2[4] = {};
#pragma unroll
            for (int s = 0; s < 8; ++s)
#pragma unroll
                for (int os = 0; os < 4; ++os) {
                    f16x8 w = *(const f16x8*)&lds[(s * 4 + os) * 512 + lane * 8];
                    acc2[os] = __builtin_amdgcn_mfma_f32_16x16x32_f16(ad[s], w, acc2[os], 0, 0, 0);
                }

            float pp[4] = {0.f, 0.f, 0.f, 0.f};
#pragma unroll
            for (int os = 0; os < 4; ++os) {
                int o = os * 16 + o_l;
                float wp = enc ? 0.f : Wp[o];
#pragma unroll
                for (int rI = 0; rI < 4; ++rI) {
                    float hc = tanhf(acc2[os][rI] + bc[o]);
                    float hn = (1.f - zreg[os][rI]) * hreg[os][rI] + zreg[os][rI] * hc;
                    hreg[os][rI] = hn;
                    pp[rI] += hn * wp;
                    int n = node0 + 4 * g + rI;
                    BfA[bf_addr(n, b, 1 + o)] = (f16)hn;
                }
            }
            if (enc) {  // next x (or 0 at seam)
                if (o_l == 0) {
#pragma unroll
                    for (int rI = 0; rI < 4; ++rI) {
                        int n = node0 + 4 * g + rI;
                        float v = (cell + 1 < TT) ? x[((size_t)b * TT + cell + 1) * NN + n] : 0.f;
                        BfA[bf_addr(n, b, 0)] = (f16)v;
                    }
                }
            } else {  // decoder: proj + out + p0 go
#pragma unroll
                for (int m = 1; m < 16; m <<= 1)
#pragma unroll
                    for (int rI = 0; rI < 4; ++rI) pp[rI] += __shfl_xor(pp[rI], m, 64);
                if (o_l == 0) {
                    int t = cell - TT;
#pragma unroll
                    for (int rI = 0; rI < 4; ++rI) {
                        int n = node0 + 4 * g + rI;
                        float v = pp[rI] + bp[0];
                        outp[((size_t)b * hor + t) * NN + n] = v;
                        BfA[bf_addr(n, b, 0)] = (f16)v;
                    }
                }
            }
        }
        if (cell + 1 < ncell) gbar(bar, tid);
    }
}

extern "C" void kernel_launch(void* const* d_in, const int* in_sizes, int n_in,
                              void* d_out, int out_size, void* d_ws, size_t ws_size,
                              hipStream_t stream) {
    const float* x   = (const float*)d_in[0];
    const float* P   = (const float*)d_in[1];
    const float* Weg = (const float*)d_in[2];
    const float* beg = (const float*)d_in[3];
    const float* Weu = (const float*)d_in[4];
    const float* beu = (const float*)d_in[5];
    const float* Wdg = (const float*)d_in[6];
    const float* bdg = (const float*)d_in[7];
    const float* Wdu = (const float*)d_in[8];
    const float* bdu = (const float*)d_in[9];
    const float* Wp  = (const float*)d_in[10];
    const float* bp  = (const float*)d_in[11];
    float* out = (float*)d_out;
    int hor = out_size / (BB * NN);

    float* ws = (float*)d_ws;
    size_t off = 0;
    f16* BfA  = (f16*)(ws + off); off += 16 * 32 * PSUB * 64 * 8 / 2;  // 2.62 MB
    f16* BfB  = (f16*)(ws + off); off += 16 * 32 * PSUB * 64 * 8 / 2;
    f16* Af   = (f16*)(ws + off); off += (size_t)MSUB * 16 * 512 / 2;
    f16* WfGe = (f16*)(ws + off); off += 8 * 8 * 64 * 8 / 2;
    f16* WfGd = (f16*)(ws + off); off += 8 * 8 * 64 * 8 / 2;
    f16* WfCe = (f16*)(ws + off); off += 8 * 4 * 64 * 8 / 2;
    f16* WfCd = (f16*)(ws + off); off += 8 * 4 * 64 * 8 / 2;
    unsigned* bar = (unsigned*)(ws + off); off += 64;

    size_t bf_bytes = (size_t)16 * 32 * PSUB * 64 * 8 * sizeof(f16);
    hipMemsetAsync(BfA, 0, bf_bytes, stream);
    hipMemsetAsync(BfB, 0, bf_bytes, stream);
    hipMemsetAsync(bar, 0, 64 * sizeof(float), stream);

    conv_a<<<(MSUB * 16 * 512 / 8) / 256, 256, 0, stream>>>(P, Af);
    conv_w<<<16, 256, 0, stream>>>(Weg, 128, 8, WfGe);
    conv_w<<<16, 256, 0, stream>>>(Wdg, 128, 8, WfGd);
    conv_w<<<8,  256, 0, stream>>>(Weu, 64, 4, WfCe);
    conv_w<<<8,  256, 0, stream>>>(Wdu, 64, 4, WfCd);
    upd_x<<<RTOT / 256, 256, 0, stream>>>(x, 0, BfA);

    persist<<<256, 256, 0, stream>>>(Af, BfA, BfB, WfGe, WfCe, WfGd, WfCd,
                                     beg, beu, bdg, bdu, x, Wp, bp, out, hor, bar);
}

// Round 12
// 562.518 us; speedup vs baseline: 3.5096x; 3.5096x over previous
//
#include <hip/hip_runtime.h>
#include <hip/hip_bf16.h>
#include <math.h>

// Problem constants
#define BB 32
#define TT 12
#define NN 512
#define HH 64
#define DIN 65
#define MSUB 96        // ROWS/16 (ROWS = 3*512)
#define RTOT 16384     // BB*NN dense rows
#define PSUB 5         // 80 padded cols per batch
#define BSTG 5120      // f16 per B staging buffer (10 subtiles x 512)

typedef _Float16 f16;
typedef f16 f16x8 __attribute__((ext_vector_type(8)));
typedef float f32x4 __attribute__((ext_vector_type(4)));

#define GLD_LDS16(g, l) \
    __builtin_amdgcn_global_load_lds((const __attribute__((address_space(1))) void*)(g), \
                                     (__attribute__((address_space(3))) void*)(l), 16, 0, 0)

// Bf element address: node j (K-dim), batch b, local col p in [0,80)
__device__ __forceinline__ size_t bf_addr(int j, int b, int p) {
    return ((size_t)(((j >> 5) * 32 + b) * PSUB + (p >> 4)) * 64 + ((j >> 3) & 3) * 16 + (p & 15)) * 8 + (j & 7);
}

// ---------------- convert P (f32, 1536x512 row-major) -> fragment-major f16 A ----------------
__global__ __launch_bounds__(256) void conv_a(const float* __restrict__ P, f16* __restrict__ Af) {
    int u = blockIdx.x * 256 + threadIdx.x;  // 1536*512/8 slots
    int lane = u & 63;
    int su = u >> 6;
    int ks = su / MSUB, ms = su - ks * MSUB;
    int m = ms * 16 + (lane & 15);
    int k = ks * 32 + (lane >> 4) * 8;
    const float* src = &P[(size_t)m * 512 + k];
    f16x8 v;
#pragma unroll
    for (int i = 0; i < 8; ++i) v[i] = (f16)src[i];
    *(f16x8*)&Af[(size_t)u * 8] = v;
}

// -------- convert dense weight (195 x O f32) -> K-permuted fragment pack matching in-reg S^T --
__global__ __launch_bounds__(256) void conv_w(const float* __restrict__ W, int O, int OS,
                                              f16* __restrict__ Wf) {
    int u = blockIdx.x * 256 + threadIdx.x;
    if (u >= 8 * OS * 64) return;
    int lane = u & 63, slot = u >> 6;
    int s = slot / OS, os = slot - s * OS;
    int o = os * 16 + (lane & 15);
    int g = lane >> 4;
    f16x8 v;
#pragma unroll
    for (int i = 0; i < 8; ++i) {
        int f = 2 * s + (i >= 4 ? 1 : 0);
        int kl = f / 5, ps = f - kl * 5;
        int p = ps * 16 + 4 * g + (i & 3);
        v[i] = (f < 15 && p < 65) ? (f16)W[(size_t)(kl * 65 + p) * O + o] : (f16)0.f;
    }
    *(f16x8*)&Wf[(size_t)u * 8] = v;
}

// ---------------- write x[b,0,:,0] into Bf p=0 col (prologue) ----------------
__global__ __launch_bounds__(256) void upd_x(const float* __restrict__ x, int t,
                                             f16* __restrict__ Bf) {
    int idx = blockIdx.x * 256 + threadIdx.x;
    if (idx >= RTOT) return;
    int b = idx >> 9, n = idx & 511;
    Bf[bf_addr(n, b, 0)] = (f16)x[((size_t)b * TT + t) * NN + n];
}

// ---------------- B staging: 10 subtiles, waves take 3/3/2/2 ----------------
__device__ __forceinline__ void stage_b(const f16* __restrict__ BfIn, f16* __restrict__ lds,
                                        int b, int wave, int lane, int d, int it) {
#pragma unroll
    for (int qi = 0; qi < 3; ++qi) {
        int q = qi * 4 + wave;
        if (q < 10) {
            int ksl = q / 5, ps = q - ksl * 5;
            const f16* src = &BfIn[((size_t)(((it * 2 + ksl) * 32 + b) * PSUB + ps) * 64 + lane) * 8];
            GLD_LDS16(src, &lds[d * BSTG + q * 512 + lane * 8]);
        }
    }
}

// ---------------- A fragments: per-wave private -> direct global->VGPR, double-pipelined ------
__device__ __forceinline__ void load_a(const f16* __restrict__ Af, f16x8 (&a)[6],
                                       int mb, int wave, int lane, int it) {
#pragma unroll
    for (int s = 0; s < 2; ++s)
#pragma unroll
        for (int k = 0; k < 3; ++k)
            a[s * 3 + k] = *(const f16x8*)&Af[((size_t)((it * 2 + s) * MSUB + k * 32 + mb * 4 + wave) * 64 + lane) * 8];
}

__device__ __forceinline__ void compute_step(const f16* __restrict__ lds, int d, int lane,
                                             const f16x8 (&a)[6], f32x4 (&acc)[15]) {
#pragma unroll
    for (int s = 0; s < 2; ++s) {
        f16x8 bfr[5];
#pragma unroll
        for (int ps = 0; ps < 5; ++ps)
            bfr[ps] = *(const f16x8*)&lds[d * BSTG + (s * 5 + ps) * 512 + lane * 8];
#pragma unroll
        for (int k = 0; k < 3; ++k)
#pragma unroll
            for (int ps = 0; ps < 5; ++ps)
                acc[k * 5 + ps] = __builtin_amdgcn_mfma_f32_16x16x32_f16(bfr[ps], a[s * 3 + k], acc[k * 5 + ps], 0, 0, 0);
    }
}

// ---------------- mm: S^T chunk for (batch b, node-band mb) into acc[15] ----------------
__device__ __forceinline__ void gcn_mm(const f16* __restrict__ Af,
                                       const f16* __restrict__ BfIn,
                                       f16* __restrict__ lds,
                                       int b, int mb, int wave, int lane,
                                       f32x4 (&acc)[15]) {
    f16x8 a0[6], a1[6];
    load_a(Af, a0, mb, wave, lane, 0);
    stage_b(BfIn, lds, b, wave, lane, 0, 0);
#pragma unroll 1
    for (int ith = 0; ith < 4; ++ith) {
        int it0 = ith * 2;
        __syncthreads();  // B(buf0,it0) staged; prior compute on buf0 done
        stage_b(BfIn, lds, b, wave, lane, 1, it0 + 1);
        load_a(Af, a1, mb, wave, lane, it0 + 1);
        compute_step(lds, 0, lane, a0, acc);
        __syncthreads();  // B(buf1) staged; compute(buf0) done everywhere
        if (it0 + 2 < 8) {
            stage_b(BfIn, lds, b, wave, lane, 0, it0 + 2);
            load_a(Af, a0, mb, wave, lane, it0 + 2);
        }
        compute_step(lds, 1, lane, a1, acc);
    }
}

// build dense A-operand fragments from acc (K-permuted to match conv_w)
__device__ __forceinline__ void build_ad(const f32x4 (&acc)[15], f16x8 (&ad)[8]) {
#pragma unroll
    for (int s = 0; s < 8; ++s)
#pragma unroll
        for (int i = 0; i < 4; ++i) {
            ad[s][i] = (f16)acc[2 * s][i];
            ad[s][4 + i] = (s < 7) ? (f16)acc[2 * s + 1][i] : (f16)0.f;
        }
}

// ---------------- fused gates phase: mm + zr-dense + sigmoid; z->zf, r*h->BfOut; p0 copy ------
// blockIdx = mb*32 + b  =>  XCD = b%8: Bf rows for batch b stay XCD-local across phases.
__global__ __launch_bounds__(256, 1) void fused_gates(const f16* __restrict__ Af,
                                                      const f16* __restrict__ BfIn,
                                                      f16* __restrict__ BfOut,
                                                      const f16* __restrict__ Wf,
                                                      const float* __restrict__ bias,
                                                      const float* __restrict__ hf,
                                                      float* __restrict__ zf) {
    __shared__ f16 lds[32768];  // staging uses [0..2*BSTG); W uses [0..32768)
    int tid = threadIdx.x, wave = tid >> 6, lane = tid & 63;
    int b = blockIdx.x & 31, mb = blockIdx.x >> 5;
    f32x4 acc[15] = {};
    gcn_mm(Af, BfIn, lds, b, mb, wave, lane, acc);

    f16x8 ad[8];
    build_ad(acc, ad);

    __syncthreads();  // staging reads done; reuse lds for W
#pragma unroll
    for (int qi = 0; qi < 16; ++qi) {
        int q = qi * 4 + wave;  // 64 W subtiles
        GLD_LDS16(&Wf[((size_t)q * 64 + lane) * 8], &lds[q * 512 + lane * 8]);
    }
    __syncthreads();

    f32x4 acc2[8] = {};
#pragma unroll
    for (int s = 0; s < 8; ++s)
#pragma unroll
        for (int os = 0; os < 8; ++os) {
            f16x8 w = *(const f16x8*)&lds[(s * 8 + os) * 512 + lane * 8];
            acc2[os] = __builtin_amdgcn_mfma_f32_16x16x32_f16(ad[s], w, acc2[os], 0, 0, 0);
        }

    int o_l = lane & 15, g = lane >> 4;
    int node0 = mb * 64 + wave * 16;
    int rf = b * 32 + mb * 4 + wave;
#pragma unroll
    for (int os = 0; os < 4; ++os) {  // z
        f32x4 v;
#pragma unroll
        for (int rI = 0; rI < 4; ++rI)
            v[rI] = 1.f / (1.f + expf(-(acc2[os][rI] + bias[os * 16 + o_l])));
        *(f32x4*)&zf[((size_t)(rf * 4 + os) * 64 + lane) * 4] = v;
    }
#pragma unroll
    for (int os = 4; os < 8; ++os) {  // r -> r*h
        int osh = os - 4;
        f32x4 hv = *(const f32x4*)&hf[((size_t)(rf * 4 + osh) * 64 + lane) * 4];
#pragma unroll
        for (int rI = 0; rI < 4; ++rI) {
            float rr = 1.f / (1.f + expf(-(acc2[os][rI] + bias[64 + osh * 16 + o_l])));
            int n = node0 + 4 * g + rI;
            BfOut[bf_addr(n, b, 1 + osh * 16 + o_l)] = (f16)(rr * hv[rI]);
        }
    }
    if (tid < 64) {  // p0 col copy (x or go)
        int n = mb * 64 + tid;
        BfOut[bf_addr(n, b, 0)] = BfIn[bf_addr(n, b, 0)];
    }
}

// -------- fused cand phase: mm + cand-dense + tanh + GRU update; h->hf,BfOut; tail x/proj -----
__global__ __launch_bounds__(256, 1) void fused_cand(const f16* __restrict__ Af,
                                                     const f16* __restrict__ BfIn,
                                                     f16* __restrict__ BfOut,
                                                     const f16* __restrict__ Wf,
                                                     const float* __restrict__ bias,
                                                     const float* __restrict__ zf,
                                                     float* __restrict__ hf,
                                                     const float* __restrict__ xnext, int tnext,
                                                     const float* __restrict__ Wp,
                                                     const float* __restrict__ bp,
                                                     float* __restrict__ outp, int t, int hor,
                                                     int mode) {
    __shared__ f16 lds[32768];
    int tid = threadIdx.x, wave = tid >> 6, lane = tid & 63;
    int b = blockIdx.x & 31, mb = blockIdx.x >> 5;
    f32x4 acc[15] = {};
    gcn_mm(Af, BfIn, lds, b, mb, wave, lane, acc);

    f16x8 ad[8];
    build_ad(acc, ad);

    __syncthreads();
#pragma unroll
    for (int qi = 0; qi < 8; ++qi) {
        int q = qi * 4 + wave;  // 32 W subtiles
        GLD_LDS16(&Wf[((size_t)q * 64 + lane) * 8], &lds[q * 512 + lane * 8]);
    }
    __syncthreads();

    f32x4 acc2[4] = {};
#pragma unroll
    for (int s = 0; s < 8; ++s)
#pragma unroll
        for (int os = 0; os < 4; ++os) {
            f16x8 w = *(const f16x8*)&lds[(s * 4 + os) * 512 + lane * 8];
            acc2[os] = __builtin_amdgcn_mfma_f32_16x16x32_f16(ad[s], w, acc2[os], 0, 0, 0);
        }

    int o_l = lane & 15, g = lane >> 4;
    int node0 = mb * 64 + wave * 16;
    int rf = b * 32 + mb * 4 + wave;
    float pp[4] = {0.f, 0.f, 0.f, 0.f};
#pragma unroll
    for (int os = 0; os < 4; ++os) {
        int o = os * 16 + o_l;
        float wp = mode ? Wp[o] : 0.f;
        f32x4 zv = *(const f32x4*)&zf[((size_t)(rf * 4 + os) * 64 + lane) * 4];
        f32x4 hv = *(const f32x4*)&hf[((size_t)(rf * 4 + os) * 64 + lane) * 4];
        f32x4 hn;
#pragma unroll
        for (int rI = 0; rI < 4; ++rI) {
            float hc = tanhf(acc2[os][rI] + bias[o]);
            hn[rI] = (1.f - zv[rI]) * hv[rI] + zv[rI] * hc;
            pp[rI] += hn[rI] * wp;
        }
        *(f32x4*)&hf[((size_t)(rf * 4 + os) * 64 + lane) * 4] = hn;
#pragma unroll
        for (int rI = 0; rI < 4; ++rI) {
            int n = node0 + 4 * g + rI;
            BfOut[bf_addr(n, b, 1 + o)] = (f16)hn[rI];
        }
    }
    if (mode) {  // decoder: proj + out + p0
#pragma unroll
        for (int m = 1; m < 16; m <<= 1)
#pragma unroll
            for (int rI = 0; rI < 4; ++rI) pp[rI] += __shfl_xor(pp[rI], m, 64);
        if (o_l == 0) {
#pragma unroll
            for (int rI = 0; rI < 4; ++rI) {
                int n = node0 + 4 * g + rI;
                float v = pp[rI] + bp[0];
                outp[((size_t)b * hor + t) * NN + n] = v;
                BfOut[bf_addr(n, b, 0)] = (f16)v;
            }
        }
    } else {  // encoder: next x (or 0 at seam)
        if (o_l == 0) {
#pragma unroll
            for (int rI = 0; rI < 4; ++rI) {
                int n = node0 + 4 * g + rI;
                float v = xnext ? xnext[((size_t)b * TT + tnext) * NN + n] : 0.f;
                BfOut[bf_addr(n, b, 0)] = (f16)v;
            }
        }
    }
}

extern "C" void kernel_launch(void* const* d_in, const int* in_sizes, int n_in,
                              void* d_out, int out_size, void* d_ws, size_t ws_size,
                              hipStream_t stream) {
    const float* x   = (const float*)d_in[0];
    const float* P   = (const float*)d_in[1];
    const float* Weg = (const float*)d_in[2];
    const float* beg = (const float*)d_in[3];
    const float* Weu = (const float*)d_in[4];
    const float* beu = (const float*)d_in[5];
    const float* Wdg = (const float*)d_in[6];
    const float* bdg = (const float*)d_in[7];
    const float* Wdu = (const float*)d_in[8];
    const float* bdu = (const float*)d_in[9];
    const float* Wp  = (const float*)d_in[10];
    const float* bp  = (const float*)d_in[11];
    float* out = (float*)d_out;
    int hor = out_size / (BB * NN);

    float* ws = (float*)d_ws;
    size_t off = 0;
    float* hf = ws + off; off += (size_t)RTOT * HH;                    // 4 MB
    float* zf = ws + off; off += (size_t)RTOT * HH;                    // 4 MB
    f16* BfA  = (f16*)(ws + off); off += 16 * 32 * PSUB * 64 * 8 / 2;  // 2.62 MB
    f16* BfB  = (f16*)(ws + off); off += 16 * 32 * PSUB * 64 * 8 / 2;
    f16* Af   = (f16*)(ws + off); off += (size_t)MSUB * 16 * 512 / 2;
    f16* WfGe = (f16*)(ws + off); off += 8 * 8 * 64 * 8 / 2;
    f16* WfGd = (f16*)(ws + off); off += 8 * 8 * 64 * 8 / 2;
    f16* WfCe = (f16*)(ws + off); off += 8 * 4 * 64 * 8 / 2;
    f16* WfCd = (f16*)(ws + off); off += 8 * 4 * 64 * 8 / 2;

    size_t bf_bytes = (size_t)16 * 32 * PSUB * 64 * 8 * sizeof(f16);
    hipMemsetAsync(hf, 0, (size_t)RTOT * HH * sizeof(float), stream);
    hipMemsetAsync(BfA, 0, bf_bytes, stream);
    hipMemsetAsync(BfB, 0, bf_bytes, stream);

    conv_a<<<(MSUB * 16 * 512 / 8) / 256, 256, 0, stream>>>(P, Af);
    conv_w<<<16, 256, 0, stream>>>(Weg, 128, 8, WfGe);
    conv_w<<<16, 256, 0, stream>>>(Wdg, 128, 8, WfGd);
    conv_w<<<8,  256, 0, stream>>>(Weu, 64, 4, WfCe);
    conv_w<<<8,  256, 0, stream>>>(Wdu, 64, 4, WfCd);
    upd_x<<<RTOT / 256, 256, 0, stream>>>(x, 0, BfA);

    for (int t = 0; t < TT; ++t) {
        fused_gates<<<256, 256, 0, stream>>>(Af, BfA, BfB, WfGe, beg, hf, zf);
        fused_cand<<<256, 256, 0, stream>>>(Af, BfB, BfA, WfCe, beu, zf, hf,
                                            (t + 1 < TT) ? x : nullptr, t + 1,
                                            nullptr, nullptr, nullptr, 0, hor, 0);
    }
    for (int t = 0; t < hor; ++t) {
        fused_gates<<<256, 256, 0, stream>>>(Af, BfA, BfB, WfGd, bdg, hf, zf);
        fused_cand<<<256, 256, 0, stream>>>(Af, BfB, BfA, WfCd, bdu, zf, hf,
                                            nullptr, 0,
                                            Wp, bp, out, t, hor, 1);
    }
}

// Round 16
// 517.839 us; speedup vs baseline: 3.8124x; 1.0863x over previous
//
#include <hip/hip_runtime.h>
#include <hip/hip_bf16.h>
#include <math.h>

#define BB 32
#define TT 12
#define NN 512
#define HH 64
#define DIN 65
#define MSUB 96
#define RTOT 16384
#define PSUB 5
#define BSTG 5120
#define WOFF 15360

typedef _Float16 f16;
typedef f16 f16x8 __attribute__((ext_vector_type(8)));
typedef float f32x4 __attribute__((ext_vector_type(4)));

#define GLD_LDS16(g, l) \
    __builtin_amdgcn_global_load_lds((const __attribute__((address_space(1))) void*)(g), \
                                     (__attribute__((address_space(3))) void*)(l), 16, 0, 0)

__device__ __forceinline__ size_t bf_addr(int j, int b, int p) {
    return ((size_t)(((j >> 5) * 32 + b) * PSUB + (p >> 4)) * 64 + ((j >> 3) & 3) * 16 + (p & 15)) * 8 + (j & 7);
}

__global__ __launch_bounds__(256) void conv_a(const float* __restrict__ P, f16* __restrict__ Af) {
    int u = blockIdx.x * 256 + threadIdx.x;
    int lane = u & 63;
    int su = u >> 6;
    int ks = su / MSUB, ms = su - ks * MSUB;
    int m = ms * 16 + (lane & 15);
    int k = ks * 32 + (lane >> 4) * 8;
    const float* src = &P[(size_t)m * 512 + k];
    f16x8 v;
#pragma unroll
    for (int i = 0; i < 8; ++i) v[i] = (f16)src[i];
    *(f16x8*)&Af[(size_t)u * 8] = v;
}

__global__ __launch_bounds__(256) void conv_w(const float* __restrict__ W, int O, int OS,
                                              f16* __restrict__ Wf) {
    int u = blockIdx.x * 256 + threadIdx.x;
    if (u >= 8 * OS * 64) return;
    int lane = u & 63, slot = u >> 6;
    int s = slot / OS, os = slot - s * OS;
    int o = os * 16 + (lane & 15);
    int g = lane >> 4;
    f16x8 v;
#pragma unroll
    for (int i = 0; i < 8; ++i) {
        int f = 2 * s + (i >= 4 ? 1 : 0);
        int kl = f / 5, ps = f - kl * 5;
        int p = ps * 16 + 4 * g + (i & 3);
        v[i] = (f < 15 && p < 65) ? (f16)W[(size_t)(kl * 65 + p) * O + o] : (f16)0.f;
    }
    *(f16x8*)&Wf[(size_t)u * 8] = v;
}

__global__ __launch_bounds__(256) void upd_x(const float* __restrict__ x, int t,
                                             f16* __restrict__ Bf) {
    int idx = blockIdx.x * 256 + threadIdx.x;
    if (idx >= RTOT) return;
    int b = idx >> 9, n = idx & 511;
    Bf[bf_addr(n, b, 0)] = (f16)x[((size_t)b * TT + t) * NN + n];
}

__device__ __forceinline__ void stage_b(const f16* __restrict__ BfIn, f16* __restrict__ lds,
                                        int b, int wave, int lane, int buf, int it) {
#pragma unroll
    for (int qi = 0; qi < 3; ++qi) {
        int q = qi * 4 + wave;
        if (q < 10) {
            int ksl = q / 5, ps = q - ksl * 5;
            const f16* src = &BfIn[((size_t)(((it * 2 + ksl) * 32 + b) * PSUB + ps) * 64 + lane) * 8];
            GLD_LDS16(src, &lds[buf * BSTG + q * 512 + lane * 8]);
        }
    }
}

__device__ __forceinline__ void load_a(const f16* __restrict__ Af, f16x8 (&a)[6],
                                       int mb, int wave, int lane, int it) {
#pragma unroll
    for (int s = 0; s < 2; ++s)
#pragma unroll
        for (int k = 0; k < 3; ++k)
            a[s * 3 + k] = *(const f16x8*)&Af[((size_t)((it * 2 + s) * MSUB + k * 32 + mb * 4 + wave) * 64 + lane) * 8];
}

__device__ __forceinline__ void compute_step(const f16* __restrict__ lds, int d, int lane,
                                             const f16x8 (&a)[6], f32x4 (&acc)[15]) {
#pragma unroll
    for (int s = 0; s < 2; ++s) {
        f16x8 bfr[5];
#pragma unroll
        for (int ps = 0; ps < 5; ++ps)
            bfr[ps] = *(const f16x8*)&lds[d * BSTG + (s * 5 + ps) * 512 + lane * 8];
#pragma unroll
        for (int k = 0; k < 3; ++k)
#pragma unroll
            for (int ps = 0; ps < 5; ++ps)
                acc[k * 5 + ps] = __builtin_amdgcn_mfma_f32_16x16x32_f16(bfr[ps], a[s * 3 + k], acc[k * 5 + ps], 0, 0, 0);
    }
}

// 3-buffer counted-vmcnt pipeline (T3/T4), one raw barrier per K64-step.
__device__ __forceinline__ void gcn_mm(const f16* __restrict__ Af,
                                       const f16* __restrict__ BfIn,
                                       f16* __restrict__ lds,
                                       int b, int mb, int wave, int lane,
                                       f32x4 (&acc)[15]) {
    f16x8 a0[6], a1[6], a2[6];
    stage_b(BfIn, lds, b, wave, lane, 0, 0);
    load_a(Af, a0, mb, wave, lane, 0);
    stage_b(BfIn, lds, b, wave, lane, 1, 1);
    load_a(Af, a1, mb, wave, lane, 1);
#pragma unroll
    for (int it = 0; it < 8; ++it) {
        if (it < 7) {
            asm volatile("s_waitcnt vmcnt(12)" ::: "memory");
        } else {
            asm volatile("s_waitcnt vmcnt(6)" ::: "memory");
        }
        __builtin_amdgcn_sched_barrier(0);
        __builtin_amdgcn_s_barrier();
        __builtin_amdgcn_sched_barrier(0);
        if (it + 2 < 8) {
            stage_b(BfIn, lds, b, wave, lane, (it + 2) % 3, it + 2);
            if ((it + 2) % 3 == 0)      load_a(Af, a0, mb, wave, lane, it + 2);
            else if ((it + 2) % 3 == 1) load_a(Af, a1, mb, wave, lane, it + 2);
            else                        load_a(Af, a2, mb, wave, lane, it + 2);
        }
        __builtin_amdgcn_sched_barrier(0);
        if (it % 3 == 0)      compute_step(lds, 0, lane, a0, acc);
        else if (it % 3 == 1) compute_step(lds, 1, lane, a1, acc);
        else                  compute_step(lds, 2, lane, a2, acc);
    }
}

__device__ __forceinline__ void build_ad(const f32x4 (&acc)[15], f16x8 (&ad)[8]) {
#pragma unroll
    for (int s = 0; s < 8; ++s)
#pragma unroll
        for (int i = 0; i < 4; ++i) {
            ad[s][i] = (f16)acc[2 * s][i];
            ad[s][4 + i] = (s < 7) ? (f16)acc[2 * s + 1][i] : (f16)0.f;
        }
}

// blockIdx = mb*32 + b: XCD = b%8, so Bf rows for batch b stay XCD-local across phases.
__global__ __launch_bounds__(256, 1) void fused_gates(const f16* __restrict__ Af,
                                                      const f16* __restrict__ BfIn,
                                                      f16* __restrict__ BfOut,
                                                      const f16* __restrict__ Wf,
                                                      const float* __restrict__ bias,
                                                      const float* __restrict__ hf,
                                                      float* __restrict__ zf) {
    __shared__ f16 lds[WOFF + 32768];
    int tid = threadIdx.x, wave = tid >> 6, lane = tid & 63;
    int b = blockIdx.x & 31, mb = blockIdx.x >> 5;

#pragma unroll
    for (int qi = 0; qi < 16; ++qi) {
        int q = qi * 4 + wave;
        GLD_LDS16(&Wf[((size_t)q * 64 + lane) * 8], &lds[WOFF + q * 512 + lane * 8]);
    }

    f32x4 acc[15] = {};
    gcn_mm(Af, BfIn, lds, b, mb, wave, lane, acc);

    f16x8 ad[8];
    build_ad(acc, ad);

    f32x4 acc2[8] = {};
#pragma unroll
    for (int s = 0; s < 8; ++s)
#pragma unroll
        for (int os = 0; os < 8; ++os) {
            f16x8 w = *(const f16x8*)&lds[WOFF + (s * 8 + os) * 512 + lane * 8];
            acc2[os] = __builtin_amdgcn_mfma_f32_16x16x32_f16(ad[s], w, acc2[os], 0, 0, 0);
        }

    int o_l = lane & 15, g = lane >> 4;
    int node0 = mb * 64 + wave * 16;
    int rf = b * 32 + mb * 4 + wave;
#pragma unroll
    for (int os = 0; os < 4; ++os) {
        f32x4 v;
#pragma unroll
        for (int rI = 0; rI < 4; ++rI)
            v[rI] = 1.f / (1.f + expf(-(acc2[os][rI] + bias[os * 16 + o_l])));
        *(f32x4*)&zf[((size_t)(rf * 4 + os) * 64 + lane) * 4] = v;
    }
#pragma unroll
    for (int os = 4; os < 8; ++os) {
        int osh = os - 4;
        f32x4 hv = *(const f32x4*)&hf[((size_t)(rf * 4 + osh) * 64 + lane) * 4];
#pragma unroll
        for (int rI = 0; rI < 4; ++rI) {
            float rr = 1.f / (1.f + expf(-(acc2[os][rI] + bias[64 + osh * 16 + o_l])));
            int n = node0 + 4 * g + rI;
            BfOut[bf_addr(n, b, 1 + osh * 16 + o_l)] = (f16)(rr * hv[rI]);
        }
    }
    if (tid < 64) {
        int n = mb * 64 + tid;
        BfOut[bf_addr(n, b, 0)] = BfIn[bf_addr(n, b, 0)];
    }
}

__global__ __launch_bounds__(256, 1) void fused_cand(const f16* __restrict__ Af,
                                                     const f16* __restrict__ BfIn,
                                                     f16* __restrict__ BfOut,
                                                     const f16* __restrict__ Wf,
                                                     const float* __restrict__ bias,
                                                     const float* __restrict__ zf,
                                                     float* __restrict__ hf,
                                                     const float* __restrict__ xnext, int tnext,
                                                     const float* __restrict__ Wp,
                                                     const float* __restrict__ bp,
                                                     float* __restrict__ outp, int t, int hor,
                                                     int mode) {
    __shared__ f16 lds[WOFF + 16384];
    int tid = threadIdx.x, wave = tid >> 6, lane = tid & 63;
    int b = blockIdx.x & 31, mb = blockIdx.x >> 5;

#pragma unroll
    for (int qi = 0; qi < 8; ++qi) {
        int q = qi * 4 + wave;
        GLD_LDS16(&Wf[((size_t)q * 64 + lane) * 8], &lds[WOFF + q * 512 + lane * 8]);
    }

    f32x4 acc[15] = {};
    gcn_mm(Af, BfIn, lds, b, mb, wave, lane, acc);

    f16x8 ad[8];
    build_ad(acc, ad);

    f32x4 acc2[4] = {};
#pragma unroll
    for (int s = 0; s < 8; ++s)
#pragma unroll
        for (int os = 0; os < 4; ++os) {
            f16x8 w = *(const f16x8*)&lds[WOFF + (s * 4 + os) * 512 + lane * 8];
            acc2[os] = __builtin_amdgcn_mfma_f32_16x16x32_f16(ad[s], w, acc2[os], 0, 0, 0);
        }

    int o_l = lane & 15, g = lane >> 4;
    int node0 = mb * 64 + wave * 16;
    int rf = b * 32 + mb * 4 + wave;
    float pp[4] = {0.f, 0.f, 0.f, 0.f};
#pragma unroll
    for (int os = 0; os < 4; ++os) {
        int o = os * 16 + o_l;
        float wp = mode ? Wp[o] : 0.f;
        f32x4 zv = *(const f32x4*)&zf[((size_t)(rf * 4 + os) * 64 + lane) * 4];
        f32x4 hv = *(const f32x4*)&hf[((size_t)(rf * 4 + os) * 64 + lane) * 4];
        f32x4 hn;
#pragma unroll
        for (int rI = 0; rI < 4; ++rI) {
            float hc = tanhf(acc2[os][rI] + bias[o]);
            hn[rI] = (1.f - zv[rI]) * hv[rI] + zv[rI] * hc;
            pp[rI] += hn[rI] * wp;
        }
        *(f32x4*)&hf[((size_t)(rf * 4 + os) * 64 + lane) * 4] = hn;
#pragma unroll
        for (int rI = 0; rI < 4; ++rI) {
            int n = node0 + 4 * g + rI;
            BfOut[bf_addr(n, b, 1 + o)] = (f16)hn[rI];
        }
    }
    if (mode) {
#pragma unroll
        for (int m = 1; m < 16; m <<= 1)
#pragma unroll
            for (int rI = 0; rI < 4; ++rI) pp[rI] += __shfl_xor(pp[rI], m, 64);
        if (o_l == 0) {
#pragma unroll
            for (int rI = 0; rI < 4; ++rI) {
                int n = node0 + 4 * g + rI;
                float v = pp[rI] + bp[0];
                outp[((size_t)b * hor + t) * NN + n] = v;
                BfOut[bf_addr(n, b, 0)] = (f16)v;
            }
        }
    } else {
        if (o_l == 0) {
#pragma unroll
            for (int rI = 0; rI < 4; ++rI) {
                int n = node0 + 4 * g + rI;
                float v = xnext ? xnext[((size_t)b * TT + tnext) * NN + n] : 0.f;
                BfOut[bf_addr(n, b, 0)] = (f16)v;
            }
        }
    }
}

extern "C" void kernel_launch(void* const* d_in, const int* in_sizes, int n_in,
                              void* d_out, int out_size, void* d_ws, size_t ws_size,
                              hipStream_t stream) {
    const float* x   = (const float*)d_in[0];
    const float* P   = (const float*)d_in[1];
    const float* Weg = (const float*)d_in[2];
    const float* beg = (const float*)d_in[3];
    const float* Weu = (const float*)d_in[4];
    const float* beu = (const float*)d_in[5];
    const float* Wdg = (const float*)d_in[6];
    const float* bdg = (const float*)d_in[7];
    const float* Wdu = (const float*)d_in[8];
    const float* bdu = (const float*)d_in[9];
    const float* Wp  = (const float*)d_in[10];
    const float* bp  = (const float*)d_in[11];
    float* out = (float*)d_out;
    int hor = out_size / (BB * NN);

    float* ws = (float*)d_ws;
    size_t off = 0;
    float* hf = ws + off; off += (size_t)RTOT * HH;
    float* zf = ws + off; off += (size_t)RTOT * HH;
    f16* BfA  = (f16*)(ws + off); off += 16 * 32 * PSUB * 64 * 8 / 2;
    f16* BfB  = (f16*)(ws + off); off += 16 * 32 * PSUB * 64 * 8 / 2;
    f16* Af   = (f16*)(ws + off); off += (size_t)MSUB * 16 * 512 / 2;
    f16* WfGe = (f16*)(ws + off); off += 8 * 8 * 64 * 8 / 2;
    f16* WfGd = (f16*)(ws + off); off += 8 * 8 * 64 * 8 / 2;
    f16* WfCe = (f16*)(ws + off); off += 8 * 4 * 64 * 8 / 2;
    f16* WfCd = (f16*)(ws + off); off += 8 * 4 * 64 * 8 / 2;

    size_t bf_bytes = (size_t)16 * 32 * PSUB * 64 * 8 * sizeof(f16);
    hipMemsetAsync(hf, 0, (size_t)RTOT * HH * sizeof(float), stream);
    hipMemsetAsync(BfA, 0, bf_bytes, stream);
    hipMemsetAsync(BfB, 0, bf_bytes, stream);

    conv_a<<<(MSUB * 16 * 512 / 8) / 256, 256, 0, stream>>>(P, Af);
    conv_w<<<16, 256, 0, stream>>>(Weg, 128, 8, WfGe);
    conv_w<<<16, 256, 0, stream>>>(Wdg, 128, 8, WfGd);
    conv_w<<<8,  256, 0, stream>>>(Weu, 64, 4, WfCe);
    conv_w<<<8,  256, 0, stream>>>(Wdu, 64, 4, WfCd);
    upd_x<<<RTOT / 256, 256, 0, stream>>>(x, 0, BfA);

    for (int t = 0; t < TT; ++t) {
        fused_gates<<<256, 256, 0, stream>>>(Af, BfA, BfB, WfGe, beg, hf, zf);
        fused_cand<<<256, 256, 0, stream>>>(Af, BfB, BfA, WfCe, beu, zf, hf,
                                            (t + 1 < TT) ? x : nullptr, t + 1,
                                            nullptr, nullptr, nullptr, 0, hor, 0);
    }
    for (int t = 0; t < hor; ++t) {
        fused_gates<<<256, 256, 0, stream>>>(Af, BfA, BfB, WfGd, bdg, hf, zf);
        fused_cand<<<256, 256, 0, stream>>>(Af, BfB, BfA, WfCd, bdu, zf, hf,
                                            nullptr, 0,
                                            Wp, bp, out, t, hor, 1);
    }
}